// Round 3
// baseline (500.878 us; speedup 1.0000x reference)
//
#include <hip/hip_runtime.h>
#include <hip/hip_bf16.h>
#include <cstdint>

typedef short short8 __attribute__((ext_vector_type(8)));
typedef float f32x4 __attribute__((ext_vector_type(4)));
typedef int   int4v __attribute__((ext_vector_type(4)));
typedef _Float16 fp16x8 __attribute__((ext_vector_type(8)));

using bf16 = __hip_bfloat16;

#define MFMA16(a, b, c) __builtin_amdgcn_mfma_f32_16x16x32_bf16((a), (b), (c), 0, 0, 0)
#define MFMAI8(a, b, c) __builtin_amdgcn_mfma_i32_16x16x64_i8((a), (b), (c), 0, 0, 0)
#define MFMAF16(a, b, c) __builtin_amdgcn_mfma_f32_16x16x32_f16((a), (b), (c), 0, 0, 0)

__device__ __forceinline__ short8 ldb8(const bf16* p) {
    return *reinterpret_cast<const short8*>(p);
}

// -------------------------------------------------------------------------
// Prep: split X and W into f16 hi/lo pairs (Dekker, scaled by 512; exact
// power-of-2 scales), cast Wp to bf16.
// -------------------------------------------------------------------------
__global__ __launch_bounds__(256) void k_prep(
    const float* __restrict__ X, const float* __restrict__ W, const float* __restrict__ Wp,
    _Float16* __restrict__ Xh, _Float16* __restrict__ Xl,
    _Float16* __restrict__ Wh, _Float16* __restrict__ Wl, bf16* __restrict__ Wpb)
{
    const int NX = 4096 * 512, NW = 1536 * 512, NP = 512 * 512;
    for (int i = blockIdx.x * 256 + threadIdx.x; i < NX + NW + NP; i += gridDim.x * 256) {
        if (i < NX) {
            const float v = X[i] * 512.0f;
            const _Float16 h = (_Float16)v;
            Xh[i] = h;
            Xl[i] = (_Float16)((v - (float)h) * 2048.0f);
        } else if (i < NX + NW) {
            const int j = i - NX;
            const float v = W[j] * 512.0f;
            const _Float16 h = (_Float16)v;
            Wh[j] = h;
            Wl[j] = (_Float16)((v - (float)h) * 2048.0f);
        } else {
            const int j = i - NX - NW;
            Wpb[j] = __float2bfloat16(Wp[j]);
        }
    }
}

// -------------------------------------------------------------------------
// Kernel 1: QKV via f16-split MFMA. Wave tile 32x32 (was 32x64) -> 6144
// waves = up to 24/CU. Arithmetic order per output identical to round-2.
// Block 64x64 (4 waves, 2x2), grid (24, 64).
// -------------------------------------------------------------------------
__global__ __launch_bounds__(256, 5) void k_qkv_f16(
    const _Float16* __restrict__ Xh, const _Float16* __restrict__ Xl,
    const _Float16* __restrict__ Wh, const _Float16* __restrict__ Wl,
    const float* __restrict__ bq,
    const float* __restrict__ qvm, const float* __restrict__ kvm, const float* __restrict__ vvm,
    const int* __restrict__ qac, const int* __restrict__ kac, const int* __restrict__ vac,
    int8_t* __restrict__ Q2, int8_t* __restrict__ K2c,
    int8_t* __restrict__ VsT, int8_t* __restrict__ VaT)
{
    const int tid = threadIdx.x;
    const int w = tid >> 6, lane = tid & 63, lo = lane & 15, hi = lane >> 4;
    const int wr = w >> 1, wc = w & 1;
    const int r0 = blockIdx.y * 64 + wr * 32;      // 32 rows for this wave
    const int c0 = blockIdx.x * 64 + wc * 32;      // 32 cols for this wave

    f32x4 hh[2][2] = {};
    f32x4 md[2][2] = {};

    const _Float16* xhp = Xh + (size_t)(r0 + lo) * 512 + hi * 8;
    const _Float16* xlp = Xl + (size_t)(r0 + lo) * 512 + hi * 8;
    const _Float16* whp = Wh + (size_t)(c0 + lo) * 512 + hi * 8;
    const _Float16* wlp = Wl + (size_t)(c0 + lo) * 512 + hi * 8;

    for (int kc = 0; kc < 16; ++kc) {
        const int ko = kc * 32;
        const fp16x8 AhA = *reinterpret_cast<const fp16x8*>(xhp + ko);
        const fp16x8 AhB = *reinterpret_cast<const fp16x8*>(xhp + ko + 16 * 512);
        const fp16x8 AlA = *reinterpret_cast<const fp16x8*>(xlp + ko);
        const fp16x8 AlB = *reinterpret_cast<const fp16x8*>(xlp + ko + 16 * 512);
        const fp16x8 BhA = *reinterpret_cast<const fp16x8*>(whp + ko);
        const fp16x8 BhB = *reinterpret_cast<const fp16x8*>(whp + ko + 16 * 512);
        const fp16x8 BlA = *reinterpret_cast<const fp16x8*>(wlp + ko);
        const fp16x8 BlB = *reinterpret_cast<const fp16x8*>(wlp + ko + 16 * 512);
        hh[0][0] = MFMAF16(AhA, BhA, hh[0][0]);
        hh[0][1] = MFMAF16(AhA, BhB, hh[0][1]);
        hh[1][0] = MFMAF16(AhB, BhA, hh[1][0]);
        hh[1][1] = MFMAF16(AhB, BhB, hh[1][1]);
        md[0][0] = MFMAF16(AhA, BlA, md[0][0]); md[0][0] = MFMAF16(AlA, BhA, md[0][0]);
        md[0][1] = MFMAF16(AhA, BlB, md[0][1]); md[0][1] = MFMAF16(AlA, BhB, md[0][1]);
        md[1][0] = MFMAF16(AhB, BlA, md[1][0]); md[1][0] = MFMAF16(AlB, BhA, md[1][0]);
        md[1][1] = MFMAF16(AhB, BlB, md[1][1]); md[1][1] = MFMAF16(AlB, BhB, md[1][1]);
    }

    // ---- epilogue: IF spikes + int8 pack ----
    const int sel = (unsigned)c0 >> 9;             // wave-uniform (32-col tiles never straddle 512)
    const float* VM = (sel == 0) ? qvm : (sel == 1) ? kvm : vvm;
    const int*   AC = (sel == 0) ? qac : (sel == 1) ? kac : vac;

    #pragma unroll
    for (int i = 0; i < 2; ++i) {
        const int rowb = r0 + i * 16 + hi * 4;     // 4 consecutive rows rowb..rowb+3
        const int b = rowb >> 10, nb = rowb & 1023;
        #pragma unroll
        for (int j = 0; j < 2; ++j) {
            const int c = c0 + j * 16 + lo;
            const int ch = c & 511;
            const int hh_ = ch >> 6, d = ch & 63;
            const int bh = b * 8 + hh_;
            const float bcol = bq[c];
            int sp[4], a4[4];
            #pragma unroll
            for (int r = 0; r < 4; ++r) {
                const size_t gi = (size_t)(bh * 1024 + nb + r) * 64 + d;
                const float vm = VM[gi];
                const int a0 = AC[gi];
                const float val = fmaf(md[i][j][r], 0x1p-11f, hh[i][j][r]) * 0x1p-18f;
                const float v_ = vm + (val + bcol);
                int s = ((v_ >= 1.0f) && (a0 < 7)) ? 1 : 0;
                if (v_ < 0.0f) s -= 1;
                sp[r] = s; a4[r] = a0;
            }
            if (sel == 2) {
                uchar4 us, ua;
                us.x = (uint8_t)sp[0]; us.y = (uint8_t)sp[1]; us.z = (uint8_t)sp[2]; us.w = (uint8_t)sp[3];
                ua.x = (uint8_t)a4[0]; ua.y = (uint8_t)a4[1]; ua.z = (uint8_t)a4[2]; ua.w = (uint8_t)a4[3];
                const size_t vi = (size_t)(bh * 64 + d) * 1024 + nb;   // nb % 4 == 0
                *reinterpret_cast<uchar4*>(VsT + vi) = us;
                *reinterpret_cast<uchar4*>(VaT + vi) = ua;
            } else {
                int8_t* base = ((sel == 0) ? Q2 : K2c) + (size_t)(bh * 1024 + nb) * 128 + d;
                #pragma unroll
                for (int r = 0; r < 4; ++r) {
                    const int v0 = (sel == 0) ? a4[r] + sp[r] : sp[r];
                    const int v1 = (sel == 0) ? sp[r]         : a4[r];
                    base[r * 128]      = (int8_t)v0;
                    base[r * 128 + 64] = (int8_t)v1;
                }
            }
        }
    }
}

// -------------------------------------------------------------------------
// Kernel 2: swapped-QK scores in REGISTERS (no S LDS round-trip), fast
// exp2 softmax, single reciprocal, int8 P pack (16 KB x2), i8 PV.
// LDS 33280 B -> 4 blocks/CU. 3 barriers total.
// -------------------------------------------------------------------------
__global__ __launch_bounds__(256, 4) void k_attn(
    const int8_t* __restrict__ Q2, const int8_t* __restrict__ K2c,
    const float* __restrict__ avm, const int* __restrict__ aac,
    const int8_t* __restrict__ VsT, const int8_t* __restrict__ VaT,
    bf16* __restrict__ O2)
{
    __shared__ alignas(16) char Sc[33280];
    int*   const maxb = (int*)(Sc + 32768);     // [4][16]
    float* const sumb = (float*)(Sc + 33024);   // [4][16]
    const int w = threadIdx.x >> 6, lane = threadIdx.x & 63;
    const int lo = lane & 15, hi = lane >> 4;
    const int bh = blockIdx.z * 8 + blockIdx.y;
    const int n0 = blockIdx.x * 16;

    // ---- Phase 1: swapped scores -> registers.
    // mfma(A=K-frag, B=Q-frag): lane (lo,hi) reg r holds score for
    // Q-row lo, key w*256 + t*16 + hi*4 + r. Integer-exact.
    int4v sc[16];
    {
        const int8_t* qb = Q2 + ((size_t)(bh * 1024 + n0 + lo)) * 128 + hi * 16;
        const int4v qa0 = *reinterpret_cast<const int4v*>(qb);
        const int4v qa1 = *reinterpret_cast<const int4v*>(qb + 64);
        const int8_t* kbp = K2c + ((size_t)(bh * 1024 + w * 256 + lo)) * 128 + hi * 16;
        int4v b0 = *reinterpret_cast<const int4v*>(kbp);
        int4v b1 = *reinterpret_cast<const int4v*>(kbp + 64);
        #pragma unroll
        for (int t = 0; t < 16; ++t) {
            const int4v c0f = b0, c1f = b1;
            if (t < 15) {
                kbp += 16 * 128;
                b0 = *reinterpret_cast<const int4v*>(kbp);
                b1 = *reinterpret_cast<const int4v*>(kbp + 64);
            }
            int4v s = {0, 0, 0, 0};
            s = MFMAI8(c0f, qa0, s);
            s = MFMAI8(c1f, qa1, s);
            sc[t] = s;
        }
    }

    // ---- early-issue first avm/aac lines (latency hidden under reduce) ----
    const float* vmp = avm + ((size_t)(bh * 1024 + n0 + lo)) * 1024 + w * 256 + hi * 4;
    const int*   acp = aac + ((size_t)(bh * 1024 + n0 + lo)) * 1024 + w * 256 + hi * 4;
    float4 vm0 = *reinterpret_cast<const float4*>(vmp);
    int4   ac0 = *reinterpret_cast<const int4*>(acp);
    float4 vm1 = *reinterpret_cast<const float4*>(vmp + 16);
    int4   ac1 = *reinterpret_cast<const int4*>(acp + 16);

    // ---- Phase 2: row max (exact int) then sum of exp2 ----
    int mxi = sc[0][0];
    #pragma unroll
    for (int t = 0; t < 16; ++t)
        #pragma unroll
        for (int r = 0; r < 4; ++r)
            mxi = max(mxi, sc[t][r]);
    mxi = max(mxi, __shfl_xor(mxi, 16));
    mxi = max(mxi, __shfl_xor(mxi, 32));
    if (lane < 16) maxb[w * 16 + lo] = mxi;
    __syncthreads();
    const int M = max(max(maxb[lo], maxb[16 + lo]), max(maxb[32 + lo], maxb[48 + lo]));

    const float kls = 0.18033688011112042f;   // 0.125 * log2(e)
    float sum = 0.f;
    #pragma unroll
    for (int t = 0; t < 16; ++t)
        #pragma unroll
        for (int r = 0; r < 4; ++r)
            sum += exp2f(kls * (float)(sc[t][r] - M));
    sum += __shfl_xor(sum, 16);
    sum += __shfl_xor(sum, 32);
    if (lane < 16) sumb[w * 16 + lo] = sum;
    __syncthreads();
    const float Stot = (sumb[lo] + sumb[16 + lo]) + (sumb[32 + lo] + sumb[48 + lo]);
    const float rsum = 7.0f / Stot;

    // ---- Phase 3: attn-IF + int8 P pack (row-XOR swizzle), pipelined ----
    #pragma unroll
    for (int t = 0; t < 16; ++t) {
        const float4 vmc = vm0; const int4 acc_ = ac0;
        vm0 = vm1; ac0 = ac1;
        if (t < 14) {
            vm1 = *reinterpret_cast<const float4*>(vmp + (t + 2) * 16);
            ac1 = *reinterpret_cast<const int4*>(acp + (t + 2) * 16);
        }
        const float vr[4] = {vmc.x, vmc.y, vmc.z, vmc.w};
        const int   ar[4] = {acc_.x, acc_.y, acc_.z, acc_.w};
        unsigned b1v[4], b2v[4];
        #pragma unroll
        for (int i = 0; i < 4; ++i) {
            const float e_ = exp2f(kls * (float)(sc[t][i] - M));
            const float p7 = e_ * rsum;
            const float v_ = (vr[i] + 0.2f) + p7;   // v_ > 0 always (avm>=0, p7>0)
            const int a0i = ar[i];                  // in [0,7] -> neg gate never fires
            const int sp = ((v_ >= 1.0f) && (a0i < 7)) ? 1 : 0;
            b1v[i] = (unsigned)(a0i + sp);
            b2v[i] = (unsigned)sp;
        }
        const unsigned p1u = b1v[0] | (b1v[1] << 8) | (b1v[2] << 16) | (b1v[3] << 24);
        const unsigned p2u = b2v[0] | (b2v[1] << 8) | (b2v[2] << 16) | (b2v[3] << 24);
        char* pb = Sc + lo * 1024 + ((w * 256 + t * 16 + hi * 4) ^ ((lo & 7) << 4));
        *reinterpret_cast<unsigned*>(pb)         = p1u;
        *reinterpret_cast<unsigned*>(pb + 16384) = p2u;
    }
    __syncthreads();   // P fully written

    // ---- Phase 4: PV (i8 MFMA, exact i32), after-attn IF, write O2 ----
    {
        const int d0 = w * 16;
        const int8_t* vs = VsT + ((size_t)(bh * 64 + d0 + lo)) * 1024 + hi * 16;
        const int8_t* va = VaT + ((size_t)(bh * 64 + d0 + lo)) * 1024 + hi * 16;
        int4v nvs = *reinterpret_cast<const int4v*>(vs);
        int4v nva = *reinterpret_cast<const int4v*>(va);
        int4v acc = {0, 0, 0, 0};
        for (int tt = 0; tt < 16; ++tt) {
            const int4v cvs = nvs, cva = nva;
            if (tt < 15) {
                nvs = *reinterpret_cast<const int4v*>(vs + (tt + 1) * 64);
                nva = *reinterpret_cast<const int4v*>(va + (tt + 1) * 64);
            }
            const char* pb = Sc + lo * 1024 + ((tt * 64 + hi * 16) ^ ((lo & 7) << 4));
            const int4v a1 = *reinterpret_cast<const int4v*>(pb);
            const int4v a2 = *reinterpret_cast<const int4v*>(pb + 16384);
            acc = MFMAI8(a1, cvs, acc);
            acc = MFMAI8(a2, cva, acc);
        }
        #pragma unroll
        for (int r = 0; r < 4; ++r) {
            const int n = n0 + hi * 4 + r;
            const float o = (float)acc[r];          // exact integer
            const float o2 = (o >= 0.5f ? 1.f : 0.f) - (o < -0.5f ? 1.f : 0.f);
            O2[((size_t)(blockIdx.z * 1024 + n)) * 512 + blockIdx.y * 64 + d0 + lo] = __float2bfloat16(o2);
        }
    }
}

// -------------------------------------------------------------------------
// Kernel 3: Y = O2 @ Wp^T + b_proj. Wave tile 16x32 -> 4096 waves (16/CU).
// -------------------------------------------------------------------------
__global__ __launch_bounds__(256) void k_proj(
    const bf16* __restrict__ O2, const bf16* __restrict__ W, const float* __restrict__ bias,
    float* __restrict__ Y)
{
    const int w = threadIdx.x >> 6, lane = threadIdx.x & 63;
    const int lo = lane & 15, hi = lane >> 4;
    const int r0 = blockIdx.y * 16;
    const int c0 = blockIdx.x * 128 + w * 32;

    f32x4 acc[2] = {{0.f,0.f,0.f,0.f},{0.f,0.f,0.f,0.f}};
    const bf16* op = O2 + (size_t)(r0 + lo) * 512 + hi * 8;
    #pragma unroll 4
    for (int kb = 0; kb < 16; ++kb) {
        short8 a = ldb8(op + kb * 32);
        short8 b0 = ldb8(W + (size_t)(c0 + lo) * 512 + kb * 32 + hi * 8);
        short8 b1 = ldb8(W + (size_t)(c0 + 16 + lo) * 512 + kb * 32 + hi * 8);
        acc[0] = MFMA16(a, b0, acc[0]);
        acc[1] = MFMA16(a, b1, acc[1]);
    }
    #pragma unroll
    for (int t = 0; t < 2; ++t) {
        const int col = c0 + t * 16 + lo;
        const float bcol = bias[col];
        #pragma unroll
        for (int r = 0; r < 4; ++r) {
            const int rr = r0 + hi * 4 + r;
            Y[(size_t)rr * 512 + col] = acc[t][r] + bcol;
        }
    }
}

// -------------------------------------------------------------------------
extern "C" void kernel_launch(void* const* d_in, const int* in_sizes, int n_in,
                              void* d_out, int out_size, void* d_ws, size_t ws_size,
                              hipStream_t stream)
{
    const float* x     = (const float*)d_in[0];
    const float* wqkv  = (const float*)d_in[1];
    const float* bqkv  = (const float*)d_in[2];
    const float* wproj = (const float*)d_in[3];
    const float* bproj = (const float*)d_in[4];
    const float* qvm   = (const float*)d_in[5];
    const float* kvm   = (const float*)d_in[6];
    const float* vvm   = (const float*)d_in[7];
    const float* avm   = (const float*)d_in[8];
    const int*   qac   = (const int*)d_in[9];
    const int*   kac   = (const int*)d_in[10];
    const int*   vac   = (const int*)d_in[11];
    const int*   aac   = (const int*)d_in[12];

    char* p = (char*)d_ws;
    int8_t*   Q2  = (int8_t*)p;   p += (size_t)32 * 1024 * 128;     // 4 MB  [bh][n][128]
    int8_t*   K2c = (int8_t*)p;   p += (size_t)32 * 1024 * 128;     // 4 MB  [bh][m][128]
    int8_t*   VsT = (int8_t*)p;   p += (size_t)32 * 64 * 1024;      // 2 MB  [bh][d][m]
    int8_t*   VaT = (int8_t*)p;   p += (size_t)32 * 64 * 1024;      // 2 MB
    bf16*     O2  = (bf16*)p;     p += (size_t)4096 * 512 * 2;      // 4 MB  [B*N][C]
    bf16*     Wpb = (bf16*)p;     p += (size_t)512 * 512 * 2;       // 0.5MB w_proj bf16
    _Float16* Xh  = (_Float16*)p; p += (size_t)4096 * 512 * 2;      // 4 MB
    _Float16* Xl  = (_Float16*)p; p += (size_t)4096 * 512 * 2;      // 4 MB
    _Float16* Wh  = (_Float16*)p; p += (size_t)1536 * 512 * 2;      // 1.5 MB
    _Float16* Wl  = (_Float16*)p; p += (size_t)1536 * 512 * 2;      // 1.5 MB

    k_prep<<<dim3(2048), 256, 0, stream>>>(x, wqkv, wproj, Xh, Xl, Wh, Wl, Wpb);
    k_qkv_f16<<<dim3(24, 64), 256, 0, stream>>>(Xh, Xl, Wh, Wl, bqkv, qvm, kvm, vvm,
                                                qac, kac, vac, Q2, K2c, VsT, VaT);
    k_attn<<<dim3(64, 8, 4), 256, 0, stream>>>(Q2, K2c, avm, aac, VsT, VaT, O2);
    k_proj<<<dim3(4, 256), 256, 0, stream>>>(O2, Wpb, bproj, (float*)d_out);
}

// Round 4
// 463.844 us; speedup vs baseline: 1.0798x; 1.0798x over previous
//
#include <hip/hip_runtime.h>
#include <hip/hip_bf16.h>
#include <cstdint>

typedef short short8 __attribute__((ext_vector_type(8)));
typedef float f32x4 __attribute__((ext_vector_type(4)));
typedef int   int4v __attribute__((ext_vector_type(4)));
typedef _Float16 fp16x8 __attribute__((ext_vector_type(8)));

using bf16 = __hip_bfloat16;

#define MFMA16(a, b, c) __builtin_amdgcn_mfma_f32_16x16x32_bf16((a), (b), (c), 0, 0, 0)
#define MFMAI8(a, b, c) __builtin_amdgcn_mfma_i32_16x16x64_i8((a), (b), (c), 0, 0, 0)
#define MFMAF16(a, b, c) __builtin_amdgcn_mfma_f32_16x16x32_f16((a), (b), (c), 0, 0, 0)

__device__ __forceinline__ short8 ldb8(const bf16* p) {
    return *reinterpret_cast<const short8*>(p);
}

// -------------------------------------------------------------------------
// Prep: split X and W into f16 hi/lo pairs (Dekker, scaled by 512; exact
// power-of-2 scales), cast Wp to bf16.
// -------------------------------------------------------------------------
__global__ __launch_bounds__(256) void k_prep(
    const float* __restrict__ X, const float* __restrict__ W, const float* __restrict__ Wp,
    _Float16* __restrict__ Xh, _Float16* __restrict__ Xl,
    _Float16* __restrict__ Wh, _Float16* __restrict__ Wl, bf16* __restrict__ Wpb)
{
    const int NX = 4096 * 512, NW = 1536 * 512, NP = 512 * 512;
    for (int i = blockIdx.x * 256 + threadIdx.x; i < NX + NW + NP; i += gridDim.x * 256) {
        if (i < NX) {
            const float v = X[i] * 512.0f;
            const _Float16 h = (_Float16)v;
            Xh[i] = h;
            Xl[i] = (_Float16)((v - (float)h) * 2048.0f);
        } else if (i < NX + NW) {
            const int j = i - NX;
            const float v = W[j] * 512.0f;
            const _Float16 h = (_Float16)v;
            Wh[j] = h;
            Wl[j] = (_Float16)((v - (float)h) * 2048.0f);
        } else {
            const int j = i - NX - NW;
            Wpb[j] = __float2bfloat16(Wp[j]);
        }
    }
}

// -------------------------------------------------------------------------
// Kernel 1: QKV via f16-split MFMA (round-2 configuration — reverted).
// Block: 64 rows x 128 cols, 4 waves of 32x64, no LDS (direct-global frags).
// -------------------------------------------------------------------------
__global__ __launch_bounds__(256, 3) void k_qkv_f16(
    const _Float16* __restrict__ Xh, const _Float16* __restrict__ Xl,
    const _Float16* __restrict__ Wh, const _Float16* __restrict__ Wl,
    const float* __restrict__ bq,
    const float* __restrict__ qvm, const float* __restrict__ kvm, const float* __restrict__ vvm,
    const int* __restrict__ qac, const int* __restrict__ kac, const int* __restrict__ vac,
    int8_t* __restrict__ Q2, int8_t* __restrict__ K2c,
    int8_t* __restrict__ VsT, int8_t* __restrict__ VaT)
{
    const int tid = threadIdx.x;
    const int w = tid >> 6, lane = tid & 63, lo = lane & 15, hi = lane >> 4;
    const int wr = w >> 1, wc = w & 1;
    const int r0 = blockIdx.y * 64 + wr * 32;      // 32 rows for this wave
    const int c0 = blockIdx.x * 128 + wc * 64;     // 64 cols for this wave

    f32x4 hh[2][4] = {};
    f32x4 md[2][4] = {};

    const _Float16* xhp = Xh + (size_t)(r0 + lo) * 512 + hi * 8;
    const _Float16* xlp = Xl + (size_t)(r0 + lo) * 512 + hi * 8;
    const _Float16* whp = Wh + (size_t)(c0 + lo) * 512 + hi * 8;
    const _Float16* wlp = Wl + (size_t)(c0 + lo) * 512 + hi * 8;

    for (int kc = 0; kc < 16; ++kc) {
        const int ko = kc * 32;
        const fp16x8 Ah0 = *reinterpret_cast<const fp16x8*>(xhp + ko);
        const fp16x8 Ah1 = *reinterpret_cast<const fp16x8*>(xhp + ko + 16 * 512);
        const fp16x8 Al0 = *reinterpret_cast<const fp16x8*>(xlp + ko);
        const fp16x8 Al1 = *reinterpret_cast<const fp16x8*>(xlp + ko + 16 * 512);
        fp16x8 Bh[4], Bl[4];
        #pragma unroll
        for (int j = 0; j < 4; ++j) {
            Bh[j] = *reinterpret_cast<const fp16x8*>(whp + ko + j * 16 * 512);
            Bl[j] = *reinterpret_cast<const fp16x8*>(wlp + ko + j * 16 * 512);
        }
        #pragma unroll
        for (int j = 0; j < 4; ++j) {
            hh[0][j] = MFMAF16(Ah0, Bh[j], hh[0][j]);
            hh[1][j] = MFMAF16(Ah1, Bh[j], hh[1][j]);
            md[0][j] = MFMAF16(Ah0, Bl[j], md[0][j]);
            md[0][j] = MFMAF16(Al0, Bh[j], md[0][j]);
            md[1][j] = MFMAF16(Ah1, Bl[j], md[1][j]);
            md[1][j] = MFMAF16(Al1, Bh[j], md[1][j]);
        }
    }

    // ---- epilogue: IF spikes + int8 pack ----
    const int sel = (unsigned)c0 >> 9;             // block-group uniform (tiles never straddle 512)
    const float* VM = (sel == 0) ? qvm : (sel == 1) ? kvm : vvm;
    const int*   AC = (sel == 0) ? qac : (sel == 1) ? kac : vac;

    #pragma unroll
    for (int i = 0; i < 2; ++i) {
        const int rowb = r0 + i * 16 + hi * 4;     // 4 consecutive rows rowb..rowb+3
        const int b = rowb >> 10, nb = rowb & 1023;
        #pragma unroll
        for (int j = 0; j < 4; ++j) {
            const int c = c0 + j * 16 + lo;
            const int ch = c & 511;
            const int hh_ = ch >> 6, d = ch & 63;
            const int bh = b * 8 + hh_;
            const float bcol = bq[c];
            int sp[4], a4[4];
            #pragma unroll
            for (int r = 0; r < 4; ++r) {
                const size_t gi = (size_t)(bh * 1024 + nb + r) * 64 + d;
                const float vm = VM[gi];
                const int a0 = AC[gi];
                const float val = fmaf(md[i][j][r], 0x1p-11f, hh[i][j][r]) * 0x1p-18f;
                const float v_ = vm + (val + bcol);
                int s = ((v_ >= 1.0f) && (a0 < 7)) ? 1 : 0;
                if (v_ < 0.0f) s -= 1;
                sp[r] = s; a4[r] = a0;
            }
            if (sel == 2) {
                uchar4 us, ua;
                us.x = (uint8_t)sp[0]; us.y = (uint8_t)sp[1]; us.z = (uint8_t)sp[2]; us.w = (uint8_t)sp[3];
                ua.x = (uint8_t)a4[0]; ua.y = (uint8_t)a4[1]; ua.z = (uint8_t)a4[2]; ua.w = (uint8_t)a4[3];
                const size_t vi = (size_t)(bh * 64 + d) * 1024 + nb;   // nb % 4 == 0
                *reinterpret_cast<uchar4*>(VsT + vi) = us;
                *reinterpret_cast<uchar4*>(VaT + vi) = ua;
            } else {
                int8_t* base = ((sel == 0) ? Q2 : K2c) + (size_t)(bh * 1024 + nb) * 128 + d;
                #pragma unroll
                for (int r = 0; r < 4; ++r) {
                    const int v0 = (sel == 0) ? a4[r] + sp[r] : sp[r];
                    const int v1 = (sel == 0) ? sp[r]         : a4[r];
                    base[r * 128]      = (int8_t)v0;
                    base[r * 128 + 64] = (int8_t)v1;
                }
            }
        }
    }
}

// -------------------------------------------------------------------------
// Kernel 2: swapped-QK register scores, exp2 softmax, deep load pipelines:
// K-frags depth-2, avm/aac burst-4 before reduction + rolling depth-4.
// LDS 33280 B -> 4 blocks/CU. 3 barriers.
// -------------------------------------------------------------------------
__global__ __launch_bounds__(256, 4) void k_attn(
    const int8_t* __restrict__ Q2, const int8_t* __restrict__ K2c,
    const float* __restrict__ avm, const int* __restrict__ aac,
    const int8_t* __restrict__ VsT, const int8_t* __restrict__ VaT,
    bf16* __restrict__ O2)
{
    __shared__ alignas(16) char Sc[33280];
    int*   const maxb = (int*)(Sc + 32768);     // [4][16]
    float* const sumb = (float*)(Sc + 33024);   // [4][16]
    const int w = threadIdx.x >> 6, lane = threadIdx.x & 63;
    const int lo = lane & 15, hi = lane >> 4;
    const int bh = blockIdx.z * 8 + blockIdx.y;
    const int n0 = blockIdx.x * 16;

    // ---- Phase 1: swapped scores -> registers (K prefetch depth 2) ----
    int4v sc[16];
    {
        const int8_t* qb = Q2 + ((size_t)(bh * 1024 + n0 + lo)) * 128 + hi * 16;
        const int4v qa0 = *reinterpret_cast<const int4v*>(qb);
        const int4v qa1 = *reinterpret_cast<const int4v*>(qb + 64);
        const int8_t* kbp = K2c + ((size_t)(bh * 1024 + w * 256 + lo)) * 128 + hi * 16;
        int4v b0[2], b1[2];
        b0[0] = *reinterpret_cast<const int4v*>(kbp);
        b1[0] = *reinterpret_cast<const int4v*>(kbp + 64);
        b0[1] = *reinterpret_cast<const int4v*>(kbp + 2048);
        b1[1] = *reinterpret_cast<const int4v*>(kbp + 2048 + 64);
        #pragma unroll
        for (int t = 0; t < 16; ++t) {
            const int4v c0f = b0[t & 1], c1f = b1[t & 1];
            if (t < 14) {
                const int8_t* np = kbp + (t + 2) * 2048;
                b0[t & 1] = *reinterpret_cast<const int4v*>(np);
                b1[t & 1] = *reinterpret_cast<const int4v*>(np + 64);
            }
            int4v s = {0, 0, 0, 0};
            s = MFMAI8(c0f, qa0, s);
            s = MFMAI8(c1f, qa1, s);
            sc[t] = s;
        }
    }

    // ---- burst-4 avm/aac prefetch (latency covered by the reductions) ----
    const float* vmp = avm + ((size_t)(bh * 1024 + n0 + lo)) * 1024 + w * 256 + hi * 4;
    const int*   acp = aac + ((size_t)(bh * 1024 + n0 + lo)) * 1024 + w * 256 + hi * 4;
    float4 vmr[4]; int4 acr[4];
    #pragma unroll
    for (int j = 0; j < 4; ++j) {
        vmr[j] = *reinterpret_cast<const float4*>(vmp + j * 16);
        acr[j] = *reinterpret_cast<const int4*>(acp + j * 16);
    }

    // ---- Phase 2: row max (exact int) then sum of exp2 ----
    int mxi = sc[0][0];
    #pragma unroll
    for (int t = 0; t < 16; ++t)
        #pragma unroll
        for (int r = 0; r < 4; ++r)
            mxi = max(mxi, sc[t][r]);
    mxi = max(mxi, __shfl_xor(mxi, 16));
    mxi = max(mxi, __shfl_xor(mxi, 32));
    if (lane < 16) maxb[w * 16 + lo] = mxi;
    __syncthreads();
    const int M = max(max(maxb[lo], maxb[16 + lo]), max(maxb[32 + lo], maxb[48 + lo]));

    const float kls = 0.18033688011112042f;   // 0.125 * log2(e)
    float sum = 0.f;
    #pragma unroll
    for (int t = 0; t < 16; ++t)
        #pragma unroll
        for (int r = 0; r < 4; ++r)
            sum += exp2f(kls * (float)(sc[t][r] - M));
    sum += __shfl_xor(sum, 16);
    sum += __shfl_xor(sum, 32);
    if (lane < 16) sumb[w * 16 + lo] = sum;
    __syncthreads();
    const float Stot = (sumb[lo] + sumb[16 + lo]) + (sumb[32 + lo] + sumb[48 + lo]);
    const float rsum = 7.0f / Stot;

    // ---- Phase 3: attn-IF + int8 P pack, rolling depth-4 stream ----
    #pragma unroll
    for (int t = 0; t < 16; ++t) {
        const float4 vmc = vmr[t & 3];
        const int4  acc_ = acr[t & 3];
        if (t < 12) {
            vmr[t & 3] = *reinterpret_cast<const float4*>(vmp + (t + 4) * 16);
            acr[t & 3] = *reinterpret_cast<const int4*>(acp + (t + 4) * 16);
        }
        const float vr[4] = {vmc.x, vmc.y, vmc.z, vmc.w};
        const int   ar[4] = {acc_.x, acc_.y, acc_.z, acc_.w};
        unsigned b1v[4], b2v[4];
        #pragma unroll
        for (int i = 0; i < 4; ++i) {
            const float e_ = exp2f(kls * (float)(sc[t][i] - M));
            const float p7 = e_ * rsum;
            const float v_ = (vr[i] + 0.2f) + p7;   // v_ > 0 always (avm>=0, p7>0)
            const int a0i = ar[i];                  // in [0,7] -> neg gate never fires
            const int sp = ((v_ >= 1.0f) && (a0i < 7)) ? 1 : 0;
            b1v[i] = (unsigned)(a0i + sp);
            b2v[i] = (unsigned)sp;
        }
        const unsigned p1u = b1v[0] | (b1v[1] << 8) | (b1v[2] << 16) | (b1v[3] << 24);
        const unsigned p2u = b2v[0] | (b2v[1] << 8) | (b2v[2] << 16) | (b2v[3] << 24);
        char* pb = Sc + lo * 1024 + ((w * 256 + t * 16 + hi * 4) ^ ((lo & 7) << 4));
        *reinterpret_cast<unsigned*>(pb)         = p1u;
        *reinterpret_cast<unsigned*>(pb + 16384) = p2u;
    }
    __syncthreads();   // P fully written

    // ---- Phase 4: PV (i8 MFMA, exact i32), after-attn IF, write O2 ----
    {
        const int d0 = w * 16;
        const int8_t* vs = VsT + ((size_t)(bh * 64 + d0 + lo)) * 1024 + hi * 16;
        const int8_t* va = VaT + ((size_t)(bh * 64 + d0 + lo)) * 1024 + hi * 16;
        int4v nvs = *reinterpret_cast<const int4v*>(vs);
        int4v nva = *reinterpret_cast<const int4v*>(va);
        int4v acc = {0, 0, 0, 0};
        for (int tt = 0; tt < 16; ++tt) {
            const int4v cvs = nvs, cva = nva;
            if (tt < 15) {
                nvs = *reinterpret_cast<const int4v*>(vs + (tt + 1) * 64);
                nva = *reinterpret_cast<const int4v*>(va + (tt + 1) * 64);
            }
            const char* pb = Sc + lo * 1024 + ((tt * 64 + hi * 16) ^ ((lo & 7) << 4));
            const int4v a1 = *reinterpret_cast<const int4v*>(pb);
            const int4v a2 = *reinterpret_cast<const int4v*>(pb + 16384);
            acc = MFMAI8(a1, cvs, acc);
            acc = MFMAI8(a2, cva, acc);
        }
        #pragma unroll
        for (int r = 0; r < 4; ++r) {
            const int n = n0 + hi * 4 + r;
            const float o = (float)acc[r];          // exact integer
            const float o2 = (o >= 0.5f ? 1.f : 0.f) - (o < -0.5f ? 1.f : 0.f);
            O2[((size_t)(blockIdx.z * 1024 + n)) * 512 + blockIdx.y * 64 + d0 + lo] = __float2bfloat16(o2);
        }
    }
}

// -------------------------------------------------------------------------
// Kernel 3: Y = O2 @ Wp^T + b_proj (round-2 configuration — reverted).
// -------------------------------------------------------------------------
__global__ __launch_bounds__(256) void k_proj(
    const bf16* __restrict__ O2, const bf16* __restrict__ W, const float* __restrict__ bias,
    float* __restrict__ Y)
{
    const int w = threadIdx.x >> 6, lane = threadIdx.x & 63;
    const int lo = lane & 15, hi = lane >> 4;
    const int r0 = blockIdx.y * 16;
    const int c0 = blockIdx.x * 256 + w * 64;

    f32x4 acc[4] = {{0.f,0.f,0.f,0.f},{0.f,0.f,0.f,0.f},{0.f,0.f,0.f,0.f},{0.f,0.f,0.f,0.f}};
    const bf16* op = O2 + (size_t)(r0 + lo) * 512 + hi * 8;
    #pragma unroll 4
    for (int kb = 0; kb < 16; ++kb) {
        short8 a = ldb8(op + kb * 32);
        #pragma unroll
        for (int t = 0; t < 4; ++t) {
            short8 b = ldb8(W + (size_t)(c0 + t * 16 + lo) * 512 + kb * 32 + hi * 8);
            acc[t] = MFMA16(a, b, acc[t]);
        }
    }
    #pragma unroll
    for (int t = 0; t < 4; ++t) {
        const int col = c0 + t * 16 + lo;
        const float bcol = bias[col];
        #pragma unroll
        for (int r = 0; r < 4; ++r) {
            const int rr = r0 + hi * 4 + r;
            Y[(size_t)rr * 512 + col] = acc[t][r] + bcol;
        }
    }
}

// -------------------------------------------------------------------------
extern "C" void kernel_launch(void* const* d_in, const int* in_sizes, int n_in,
                              void* d_out, int out_size, void* d_ws, size_t ws_size,
                              hipStream_t stream)
{
    const float* x     = (const float*)d_in[0];
    const float* wqkv  = (const float*)d_in[1];
    const float* bqkv  = (const float*)d_in[2];
    const float* wproj = (const float*)d_in[3];
    const float* bproj = (const float*)d_in[4];
    const float* qvm   = (const float*)d_in[5];
    const float* kvm   = (const float*)d_in[6];
    const float* vvm   = (const float*)d_in[7];
    const float* avm   = (const float*)d_in[8];
    const int*   qac   = (const int*)d_in[9];
    const int*   kac   = (const int*)d_in[10];
    const int*   vac   = (const int*)d_in[11];
    const int*   aac   = (const int*)d_in[12];

    char* p = (char*)d_ws;
    int8_t*   Q2  = (int8_t*)p;   p += (size_t)32 * 1024 * 128;     // 4 MB  [bh][n][128]
    int8_t*   K2c = (int8_t*)p;   p += (size_t)32 * 1024 * 128;     // 4 MB  [bh][m][128]
    int8_t*   VsT = (int8_t*)p;   p += (size_t)32 * 64 * 1024;      // 2 MB  [bh][d][m]
    int8_t*   VaT = (int8_t*)p;   p += (size_t)32 * 64 * 1024;      // 2 MB
    bf16*     O2  = (bf16*)p;     p += (size_t)4096 * 512 * 2;      // 4 MB  [B*N][C]
    bf16*     Wpb = (bf16*)p;     p += (size_t)512 * 512 * 2;       // 0.5MB w_proj bf16
    _Float16* Xh  = (_Float16*)p; p += (size_t)4096 * 512 * 2;      // 4 MB
    _Float16* Xl  = (_Float16*)p; p += (size_t)4096 * 512 * 2;      // 4 MB
    _Float16* Wh  = (_Float16*)p; p += (size_t)1536 * 512 * 2;      // 1.5 MB
    _Float16* Wl  = (_Float16*)p; p += (size_t)1536 * 512 * 2;      // 1.5 MB

    k_prep<<<dim3(2048), 256, 0, stream>>>(x, wqkv, wproj, Xh, Xl, Wh, Wl, Wpb);
    k_qkv_f16<<<dim3(12, 64), 256, 0, stream>>>(Xh, Xl, Wh, Wl, bqkv, qvm, kvm, vvm,
                                                qac, kac, vac, Q2, K2c, VsT, VaT);
    k_attn<<<dim3(64, 8, 4), 256, 0, stream>>>(Q2, K2c, avm, aac, VsT, VaT, O2);
    k_proj<<<dim3(2, 256), 256, 0, stream>>>(O2, Wpb, bproj, (float*)d_out);
}